// Round 1
// 76.833 us; speedup vs baseline: 1.0311x; 1.0311x over previous
//
#include <hip/hip_runtime.h>
#include <stdint.h>

// Bit-serial conv2d closed form: term = sign(w) * ((x * |w|) >> 4)
//                                     = (x * w + A) >> 4   [arith shift]
// where A = (w<0) ? 15 : 0.  x in [0,15], w in [-8,7].
// out = relu(bias + sum_{3x3,c} term).  B=4 H=32 W=32 C=64 F=128.
// Exact in i16 (per packed half |acc| <= 7*72 = 504).

typedef short s16x2 __attribute__((ext_vector_type(2)));

#define NWPK 36864            // 9*2*512*4 packed weight dwords (2 i16 each)

// 144 blocks: weight pack only (VGPR-slice layout).
// Weight dword index: ((ki*2+g)*512 + cq*128 + f)*4 + u
//   holds channels c = cq*16 + g*8 + u*2 and c+1 for filter f, position ki.
// -> consumer thread tid=cq*128+f loads int4 at dword 4*((ki*2+g)*512 + tid).
__global__ __launch_bounds__(256) void prep_w(const float* __restrict__ kern,
                                              uint32_t* __restrict__ ws) {
    int t  = blockIdx.x * 256 + threadIdx.x;   // < 36864
    int u  = t & 3;
    int f  = (t >> 2) & 127;
    int cq = (t >> 9) & 3;
    int gk = t >> 11;                          // ki*2 + g
    int g  = gk & 1;
    int ki = gk >> 1;
    int c  = cq * 16 + g * 8 + u * 2;
    int wlo = (int)kern[(ki * 64 + c    ) * 128 + f];   // src [ki][c][f]
    int whi = (int)kern[(ki * 64 + c + 1) * 128 + f];
    ws[t] = (uint32_t)(uint16_t)(int16_t)wlo |
            ((uint32_t)(uint16_t)(int16_t)whi << 16);
}

// 512 blocks x 512 threads, single fully-resident round (2 blocks/CU).
// Block = (b, h, wq): 8 output cols x 128 f.  Thread (cq = tid>>7, f = tid&127):
// 16-channel slice, 8 pixel partials.  x staged raw->packed in LDS (fused
// padding, no ws round-trip).  Weights loaded inline (each int4 used once;
// scheduler pipelines the 18 loads across the unrolled loop).
__global__ __launch_bounds__(512, 4) void conv_main(const uint32_t* __restrict__ ws,
                                                    const float* __restrict__ input,
                                                    const float* __restrict__ bias,
                                                    float* __restrict__ out) {
    int bid = blockIdx.x;
    int wq  = bid & 3;
    int h   = (bid >> 2) & 31;
    int b   = bid >> 7;
    int tid = threadIdx.x;
    int f   = tid & 127;
    int cq  = tid >> 7;          // wave-uniform
    int w0  = wq * 8;

    __shared__ uint32_t xl[3 * 10 * 32];   // [row][col 0..9][c2]  3.75 KB
    __shared__ int prt[4 * 8 * 128];       // partial [cq][px][f]  16 KB

    // stage x-patch: 3 rows x 10 cols x 64 ch raw floats -> packed i16 pairs.
    // 480 float4 loads (16 consecutive per (row,col) segment -> coalesced).
    if (tid < 480) {
        int q   = tid & 15;                // float4 index within 64 channels
        int rc  = tid >> 4;                // [0,30): r*10 + col
        int col = rc % 10;
        int r   = rc / 10;
        int hp  = h + r - 1;
        int wp  = w0 + col - 1;
        int2 v2 = {0, 0};
        if (hp >= 0 && hp < 32 && wp >= 0 && wp < 32) {
            const float4 v = *(const float4*)&input[(((b * 32) + hp) * 32 + wp) * 64 + q * 4];
            v2.x = (int)v.x | ((int)v.y << 16);
            v2.y = (int)v.z | ((int)v.w << 16);
        }
        *(int2*)&xl[rc * 32 + q * 2] = v2;
    }

    const int4* wp4 = (const int4*)ws;
    int bv = (int)bias[f];                 // hoisted before barrier

    __syncthreads();

    s16x2 acc[8];
    #pragma unroll
    for (int i = 0; i < 8; ++i) acc[i] = (s16x2){0, 0};

    #pragma unroll
    for (int ki = 0; ki < 9; ++ki) {
        const int row = ki / 3, jj = ki % 3;
        #pragma unroll
        for (int g = 0; g < 2; ++g) {
            const int4 w4 = wp4[(ki * 2 + g) * 512 + tid];
            const uint32_t* xrow = xl + (row * 10 + jj) * 32 + cq * 8 + g * 4;
            // two half-batches of 4 px: keeps xv live-set at 16 VGPRs
            #pragma unroll
            for (int half = 0; half < 2; ++half) {
                int4 xv[4];
                #pragma unroll
                for (int p = 0; p < 4; ++p)
                    xv[p] = *(const int4*)(xrow + (half * 4 + p) * 32);  // bcast
                #pragma unroll
                for (int u = 0; u < 4; ++u) {
                    s16x2 w2 = __builtin_bit_cast(s16x2, (&w4.x)[u]);
                    s16x2 A  = (w2 >> 15) & (short)15;   // 15 where w<0
                    #pragma unroll
                    for (int p = 0; p < 4; ++p) {
                        s16x2 xs = __builtin_bit_cast(s16x2, (&xv[p].x)[u]);
                        acc[half * 4 + p] += (xs * w2 + A) >> 4;  // pk_mad/shr/add
                    }
                }
            }
        }
    }

    // per-thread horizontal add (2 channel halves), stash partials
    #pragma unroll
    for (int px = 0; px < 8; ++px) {
        int a = __builtin_bit_cast(int, acc[px]);
        prt[(cq * 8 + px) * 128 + f] = (int)(short)(a & 0xffff) + (a >> 16);
    }
    __syncthreads();

    // reduce 4 c-quarters, bias, relu, store: 1024 outputs / 512 threads
    #pragma unroll
    for (int k = 0; k < 2; ++k) {
        int px = (tid >> 7) + k * 4;
        int v = prt[(0 * 8 + px) * 128 + f] + prt[(1 * 8 + px) * 128 + f] +
                prt[(2 * 8 + px) * 128 + f] + prt[(3 * 8 + px) * 128 + f] + bv;
        out[((b * 32 + h) * 32 + w0 + px) * 128 + f] = (float)(v < 0 ? 0 : v);
    }
}

extern "C" void kernel_launch(void* const* d_in, const int* in_sizes, int n_in,
                              void* d_out, int out_size, void* d_ws, size_t ws_size,
                              hipStream_t stream) {
    const float* input  = (const float*)d_in[0];   // [4,32,32,64]
    const float* kernel = (const float*)d_in[1];   // [3,3,64,128]
    const float* bias   = (const float*)d_in[2];   // [128]
    // d_in[3] = bits (==4, baked into the closed form)

    uint32_t* ws = (uint32_t*)d_ws;                // 36864 dwords used

    prep_w<<<144, 256, 0, stream>>>(kernel, ws);
    conv_main<<<512, 512, 0, stream>>>(ws, input, bias, (float*)d_out);
}